// Round 17
// baseline (340.414 us; speedup 1.0000x reference)
//
#include <hip/hip_runtime.h>

#define DEVI __device__ __forceinline__

typedef int i32x4 __attribute__((ext_vector_type(4)));

static constexpr int Bdim = 2048;
static constexpr int Kdim = 4096;
static constexpr int Ndim = 8192;
static constexpr int BK   = 64;          // int8 k per tile
static constexpr int NT   = Kdim / BK;   // 64 tiles

#define CFENCE asm volatile("" ::: "memory")
DEVI void bar() { CFENCE; __builtin_amdgcn_s_barrier(); CFENCE; }
#define WAITLG0 asm volatile("s_waitcnt lgkmcnt(0)" ::: "memory")
#define PRIO1 __builtin_amdgcn_s_setprio(1)
#define PRIO0 __builtin_amdgcn_s_setprio(0)

DEVI int pack4(i32x4 v) {
    return (v[0] & 255) | ((v[1] & 255) << 8) | ((v[2] & 255) << 16) | (v[3] << 24);
}

// ---- fused 256x256 i8 GEMM: int32 inputs packed in-kernel during staging ----
// No pack pre-pass, no ws. Staging: global int32 (L2/L3-served) -> regs ->
// pack4 -> swizzled ds_write_b128. XCD mapping keeps each B-panel's 8 sharers
// on ONE XCD so the streaming K-window stays L2-hot (~768 KB << 4 MB).
__attribute__((amdgpu_waves_per_eu(2, 2)))
__global__ __launch_bounds__(512, 1)
void gemmf(const int* __restrict__ X32, const int* __restrict__ W32,
           const int* __restrict__ bias, const int* __restrict__ qm_p,
           const int* __restrict__ ex_p, const int* __restrict__ zp_p,
           int* __restrict__ out) {
    // LDS (16B units): 3 bufs x [A 256x4slots | B 256x4slots] = 96 KiB
    __shared__ i32x4 smem4[6144];

    const int tid  = threadIdx.x;
    const int wid  = tid >> 6;
    const int lane = tid & 63;
    const int l15  = lane & 15;
    const int lks  = lane >> 4;
    const int wr   = wid >> 2;   // 0..1
    const int wc   = wid & 3;    // 0..3

    // XCD mapping: xcd = bid&7 owns bn = xcd*4 + (bid>>6); bm = (bid>>3)&7.
    // The 8 bm-blocks sharing a bn-panel are co-resident on one XCD.
    const int bid = blockIdx.x;
    const int bm  = (bid >> 3) & 7;
    const int bn  = (bid & 7) * 4 + (bid >> 6);
    const int arow0 = bm * 256;
    const int brow0 = bn * 256;

    // T2 swizzle (r10-verified 0-conflict): phys slot = chunk ^ ((row>>1)&3)
    const int swsel = lks ^ ((l15 >> 1) & 3);
    const int a_rd16 = (wr * 128 + l15) * 4 + swsel;
    const int b_rd16 = 1024 + (wc * 64 + l15) * 4 + swsel;

    // staging: thread -> packed row ra = tid>>1, half h = tid&1 (32 ints A + 32 ints B)
    const int ra = tid >> 1, h = tid & 1;
    const int xr  = (ra >> 1) & 3;
    const int sl0 = (2 * h + 0) ^ xr;
    const int sl1 = (2 * h + 1) ^ xr;
    const i32x4* xsrc = (const i32x4*)(X32 + (size_t)(arow0 + ra) * Kdim + h * 32);
    const i32x4* wsrc = (const i32x4*)(W32 + (size_t)(brow0 + ra) * Kdim + h * 32);

    auto loadRaw = [&](int t, i32x4* rx, i32x4* rw) {
        const i32x4* sx = xsrc + (size_t)t * 16;   // BK ints = 16 i32x4
        const i32x4* sw = wsrc + (size_t)t * 16;
#pragma unroll
        for (int j = 0; j < 8; ++j) { rx[j] = sx[j]; rw[j] = sw[j]; }
    };
    auto packTo = [&](const i32x4* rx, const i32x4* rw, i32x4* pc) {
#pragma unroll
        for (int c = 0; c < 2; ++c) {
            i32x4 pa, pb;
#pragma unroll
            for (int q = 0; q < 4; ++q) {
                pa[q] = pack4(rx[c * 4 + q]);
                pb[q] = pack4(rw[c * 4 + q]);
            }
            pc[c] = pa; pc[2 + c] = pb;
        }
    };
    auto writeLds = [&](int buf, const i32x4* pc) {
        const int bb = buf * 2048;
        smem4[bb + ra * 4 + sl0]        = pc[0];
        smem4[bb + ra * 4 + sl1]        = pc[1];
        smem4[bb + 1024 + ra * 4 + sl0] = pc[2];
        smem4[bb + 1024 + ra * 4 + sl1] = pc[3];
    };

    i32x4 acc[8][4] = {};
    i32x4 rx[8], rw[8], pc[4];

    // prologue: tile 0 staged; raw loads for tile 1 in flight across the bar
    loadRaw(0, rx, rw);
    packTo(rx, rw, pc);
    writeLds(0, pc);
    loadRaw(1, rx, rw);
    WAITLG0;
    bar();

    for (int t = 0; t < NT; ++t) {
        const int cb = (t % 3) * 2048;
        i32x4 A[8], B[4];
#pragma unroll
        for (int n = 0; n < 4; ++n) B[n] = smem4[cb + b_rd16 + n * 64];
#pragma unroll
        for (int m = 0; m < 8; ++m) A[m] = smem4[cb + a_rd16 + m * 64];
        if (t + 1 < NT) packTo(rx, rw, pc);   // consumes loads issued last window
        PRIO1;
#pragma unroll
        for (int m = 0; m < 8; ++m)
#pragma unroll
            for (int n = 0; n < 4; ++n)
                acc[m][n] = __builtin_amdgcn_mfma_i32_16x16x64_i8(
                    A[m], B[n], acc[m][n], 0, 0, 0);
        PRIO0;
        if (t + 1 < NT) writeLds((t + 1) % 3, pc);   // buf's readers drained @bar(t-2)
        if (t + 2 < NT) loadRaw(t + 2, rx, rw);      // raw regs live across bar only
        WAITLG0;                                      // ds_writes visible pre-bar
        bar();
    }

    // ---------------- epilogue: requantize ----------------
    const int qm = *qm_p;
    const int ex = *ex_p;
    const int zp = *zp_p;
    const int rm = (qm < 2147418112) ? ((qm + (1 << 15)) >> 16) : 32767;
    const int shifts = 15 - ex;
    const long long rnd = (shifts > 0) ? (1LL << (shifts - 1)) : 0;

    int bv[4];
#pragma unroll
    for (int n = 0; n < 4; ++n) bv[n] = bias[brow0 + wc * 64 + n * 16 + l15];

#pragma unroll
    for (int m = 0; m < 8; ++m) {
        const int row0 = arow0 + wr * 128 + m * 16 + lks * 4;
#pragma unroll
        for (int n = 0; n < 4; ++n) {
            const int col = brow0 + wc * 64 + n * 16 + l15;
#pragma unroll
            for (int j = 0; j < 4; ++j) {
                long long v = (long long)(acc[m][n][j] + bv[n]) * rm + rnd;
                v >>= shifts;
                v += zp;
                v = v < -128 ? -128 : (v > 127 ? 127 : v);
                out[(size_t)(row0 + j) * Ndim + col] = (int)v;
            }
        }
    }
}

extern "C" void kernel_launch(void* const* d_in, const int* in_sizes, int n_in,
                              void* d_out, int out_size, void* d_ws, size_t ws_size,
                              hipStream_t stream) {
    const int* x32  = (const int*)d_in[0];
    const int* w32  = (const int*)d_in[1];
    const int* bias = (const int*)d_in[2];
    const int* qm   = (const int*)d_in[3];
    const int* ex   = (const int*)d_in[4];
    const int* zp   = (const int*)d_in[5];
    int* out = (int*)d_out;

    const int grid = (Bdim / 256) * (Ndim / 256);   // 256
    gemmf<<<grid, 512, 0, stream>>>(x32, w32, bias, qm, ex, zp, out);
}

// Round 19
// 178.393 us; speedup vs baseline: 1.9082x; 1.9082x over previous
//
#include <hip/hip_runtime.h>

#define DEVI __device__ __forceinline__

typedef int i32x4 __attribute__((ext_vector_type(4)));

static constexpr int Bdim = 2048;
static constexpr int Kdim = 4096;
static constexpr int Ndim = 8192;
static constexpr int BK   = 64;          // int8 k per tile
static constexpr int NT   = Kdim / BK;   // 64 tiles

typedef __attribute__((address_space(1))) const unsigned int gas_t;
typedef __attribute__((address_space(3))) unsigned int las_t;

DEVI void gload_lds16(const void* g, void* l) {
    __builtin_amdgcn_global_load_lds((gas_t*)g, (las_t*)l, 16, 0, 0);
}

DEVI i32x4 gload128(const void* p) {   // pinned-issue raw load (asm, no sinking)
    i32x4 r;
    asm volatile("global_load_dwordx4 %0, %1, off" : "=v"(r) : "v"(p));
    return r;
}

DEVI int pack4(i32x4 v) {
    return (v[0] & 255) | ((v[1] & 255) << 8) | ((v[2] & 255) << 16) | (v[3] << 24);
}

// ---------------- pack: int32 -> int8 (X only, 42 MB traffic ~6 us) ----------------
__global__ void pack_i32_to_i8(const int* __restrict__ in, char* __restrict__ out, int n16) {
    int i = blockIdx.x * blockDim.x + threadIdx.x;
    if (i >= n16) return;
    const i32x4* src = (const i32x4*)in + (size_t)i * 4;
    i32x4 r;
    r[0] = pack4(src[0]);
    r[1] = pack4(src[1]);
    r[2] = pack4(src[2]);
    r[3] = pack4(src[3]);
    ((i32x4*)out)[i] = r;
}

// ---- 256x256 i8 GEMM: A from packed ws via DMA; W packed IN-KERNEL (fused) ----
#define CFENCE asm volatile("" ::: "memory")
DEVI void bar() { CFENCE; __builtin_amdgcn_s_barrier(); CFENCE; }
#define WAITVM(N) asm volatile("s_waitcnt vmcnt(" #N ")" ::: "memory")
#define WAITLG0 asm volatile("s_waitcnt lgkmcnt(0)" ::: "memory")
#define SCHB __builtin_amdgcn_sched_barrier(0)
#define PRIO1 __builtin_amdgcn_s_setprio(1)
#define PRIO0 __builtin_amdgcn_s_setprio(0)

__attribute__((amdgpu_waves_per_eu(2, 2)))
__global__ __launch_bounds__(512, 2)
void gemmw(const char* __restrict__ XA8, const int* __restrict__ W32,
           const int* __restrict__ bias, const int* __restrict__ qm_p,
           const int* __restrict__ ex_p, const int* __restrict__ zp_p,
           int* __restrict__ out) {
    // LDS (16B units): 2 bufs x [A 1024 | B 1024] = 64 KiB
    __shared__ i32x4 smem4[4096];
    char* smem = (char*)smem4;

    const int tid  = threadIdx.x;
    const int wid  = tid >> 6;
    const int lane = tid & 63;
    const int l15  = lane & 15;
    const int lks  = lane >> 4;
    const int wr   = wid >> 2;   // 0..1
    const int wc   = wid & 3;    // 0..3

    // XCD mapping (r17): xcd=bid&7 owns bn = xcd*4 + (bid>>6); bm=(bid>>3)&7.
    // The 8 bm-blocks sharing a W-panel are co-resident on one XCD -> W re-reads L2-hot.
    const int bid = blockIdx.x;
    const int bm  = (bid >> 3) & 7;
    const int bn  = (bid & 7) * 4 + (bid >> 6);
    const int arow0 = bm * 256;
    const int brow0 = bn * 256;

    // T2 swizzle (r10-verified 0-conflict): phys slot = chunk ^ ((row>>1)&3)
    const int swsel = lks ^ ((l15 >> 1) & 3);
    const int a_rd16 = (wr * 128 + l15) * 4 + swsel;
    const int b_rd16 = 1024 + (wc * 64 + l15) * 4 + swsel;

    // A staging (packed, r13 path): row tid>>2 (+128), chunk st_c (inverse swizzle)
    const int st_c = (tid & 3) ^ ((tid >> 3) & 3);
    const char* agp = XA8 + (size_t)(arow0 + (tid >> 2)) * Kdim + st_c * 16;
    auto stageA = [&](int t) {
        const char* gp = agp + (size_t)t * BK;
        const int lb = (t & 1) * 32768 + tid * 16;
        gload_lds16(gp, &smem[lb]);
        gload_lds16(gp + (size_t)128 * Kdim, &smem[lb + 8192]);
    };

    // W fused staging: thread -> row ra = tid>>1, half h = tid&1 (32 raw ints)
    const int ra = tid >> 1, h = tid & 1;
    const int xr  = (ra >> 1) & 3;
    const int sl0 = (2 * h + 0) ^ xr;
    const int sl1 = (2 * h + 1) ^ xr;
    const int* wsrc = W32 + (size_t)(brow0 + ra) * Kdim + h * 32;

    i32x4 acc[8][4] = {};
    i32x4 rw[8];

    auto loadW = [&](int t) {   // 8 pinned asm loads, issued HERE
#pragma unroll
        for (int j = 0; j < 8; ++j)
            rw[j] = gload128(wsrc + (size_t)t * BK + j * 4);
    };
    auto packWriteW = [&](int t) {
        i32x4 p0, p1;
#pragma unroll
        for (int q = 0; q < 4; ++q) { p0[q] = pack4(rw[q]); p1[q] = pack4(rw[4 + q]); }
        const int bb = (t & 1) * 2048 + 1024 + ra * 4;
        smem4[bb + sl0] = p0;
        smem4[bb + sl1] = p1;
    };

    // prologue: tile 0
    loadW(0);
    stageA(0);
    WAITVM(2);          // 8 raw W done; A-DMAs outstanding
    SCHB;               // rule #18: pin pack4 BELOW the wait (reg-only ops hoist!)
    packWriteW(0);
    WAITVM(0);          // A landed
    WAITLG0;            // ds_writes visible
    bar();

    for (int t = 0; t < NT; ++t) {
        const int cb = (t & 1) * 2048;
        if (t + 1 < NT) { loadW(t + 1); stageA(t + 1); }   // issue early (pinned)
        i32x4 A[8], B[4];
#pragma unroll
        for (int n = 0; n < 4; ++n) B[n] = smem4[cb + b_rd16 + n * 64];
#pragma unroll
        for (int m = 0; m < 8; ++m) A[m] = smem4[cb + a_rd16 + m * 64];
        PRIO1;
#pragma unroll
        for (int m = 0; m < 8; ++m)
#pragma unroll
            for (int n = 0; n < 4; ++n)
                acc[m][n] = __builtin_amdgcn_mfma_i32_16x16x64_i8(
                    A[m], B[n], acc[m][n], 0, 0, 0);
        PRIO0;
        if (t + 1 < NT) {
            WAITVM(2);            // raw W(t+1) done (A-DMAs younger, 2 left)
            SCHB;                 // rule #18 fix: packs must not hoist above wait
            packWriteW(t + 1);    // buf(t+1)'s old readers drained @bar(t-1)
        }
        WAITVM(0);                // A-DMA(t+1) landed in LDS
        WAITLG0;                  // ds_writes visible block-wide after bar
        bar();
    }

    // ---------------- epilogue: requantize ----------------
    const int qm = *qm_p;
    const int ex = *ex_p;
    const int zp = *zp_p;
    const int rm = (qm < 2147418112) ? ((qm + (1 << 15)) >> 16) : 32767;
    const int shifts = 15 - ex;
    const long long rnd = (shifts > 0) ? (1LL << (shifts - 1)) : 0;

    int bv[4];
#pragma unroll
    for (int n = 0; n < 4; ++n) bv[n] = bias[brow0 + wc * 64 + n * 16 + l15];

#pragma unroll
    for (int m = 0; m < 8; ++m) {
        const int row0 = arow0 + wr * 128 + m * 16 + lks * 4;
#pragma unroll
        for (int n = 0; n < 4; ++n) {
            const int col = brow0 + wc * 64 + n * 16 + l15;
#pragma unroll
            for (int j = 0; j < 4; ++j) {
                long long v = (long long)(acc[m][n][j] + bv[n]) * rm + rnd;
                v >>= shifts;
                v += zp;
                v = v < -128 ? -128 : (v > 127 ? 127 : v);
                out[(size_t)(row0 + j) * Ndim + col] = (int)v;
            }
        }
    }
}

extern "C" void kernel_launch(void* const* d_in, const int* in_sizes, int n_in,
                              void* d_out, int out_size, void* d_ws, size_t ws_size,
                              hipStream_t stream) {
    const int* x32  = (const int*)d_in[0];
    const int* w32  = (const int*)d_in[1];
    const int* bias = (const int*)d_in[2];
    const int* qm   = (const int*)d_in[3];
    const int* ex   = (const int*)d_in[4];
    const int* zp   = (const int*)d_in[5];
    int* out = (int*)d_out;

    char* xa = (char*)d_ws;                     // packed X: 8.4 MB
    const int nx16 = Bdim * Kdim / 16;          // 524288
    pack_i32_to_i8<<<(nx16 + 255) / 256, 256, 0, stream>>>(x32, xa, nx16);

    const int grid = (Bdim / 256) * (Ndim / 256);   // 256
    gemmw<<<grid, 512, 0, stream>>>(xa, w32, bias, qm, ex, zp, out);
}